// Round 1
// 88.369 us; speedup vs baseline: 1.0112x; 1.0112x over previous
//
#include <hip/hip_runtime.h>

#define HID 10
#define NT 5
#define NS 10

__device__ __forceinline__ float sigf(float x) {
    return 1.0f / (1.0f + __expf(-x));
}
__device__ __forceinline__ float tanh_fast(float x) {
    return 2.0f / (1.0f + __expf(-2.0f * x)) - 1.0f;
}

// go1/go2 masks are jnp bool arrays; harness bool marshaling is undocumented.
// Decode defensively: int32 {0,1} -> f32 {0.0,1.0} bit patterns -> raw bytes.
__device__ __forceinline__ unsigned decode_mask(const void* p) {
    const unsigned* pu = (const unsigned*)p;
    const unsigned char* pb = (const unsigned char*)p;
    unsigned mi = 0, mf = 0, mb = 0;
    bool oki = true, okf = true;
#pragma unroll
    for (int i = 0; i < NS; ++i) {
        unsigned v = pu[i];
        if (v == 1u) mi |= (1u << i);
        else if (v != 0u) oki = false;
        if (v == 0x3F800000u) mf |= (1u << i);
        else if (v != 0u) okf = false;
        if (pb[i]) mb |= (1u << i);
    }
    return oki ? mi : (okf ? mf : mb);
}

// --- DPP helpers (row-local, 16-lane rows; bound_ctrl:0 => OOB sources read 0) ---
#define DPPI(x, CTRL) __builtin_amdgcn_update_dpp(0, (x), (CTRL), 0xF, 0xF, true)
// rotate-by-J within 16-lane row: lane i gets x[(i-J)&15], built from
// row_shr:J (dst[i]=src[i-J], 0-fill) | row_shl:16-J (dst[i]=src[i+16-J], 0-fill).
#define ROTF(x, J) __int_as_float( DPPI(__float_as_int(x), 0x110 + (J)) \
                                 | DPPI(__float_as_int(x), 0x100 + (16 - (J))) )
#define BFLY(x, CTRL) __int_as_float(DPPI(__float_as_int(x), (CTRL)))

// Layout: 16 lanes per task row. tid>>4 = task (0..7; 5..7 idle), tid&15 = u.
// h[u] lives in lanes u<10; h1/h2 (dim 20) live as plane A = [u] (u<16) and
// plane B = [16+u] (u<4). All cross-lane traffic is DPP (no ds_bpermute).
__global__ __launch_bounds__(128, 1) void rnnae_kernel(
    const float* __restrict__ omega, const float* __restrict__ noise,
    const void* __restrict__ go1, const void* __restrict__ go2,
    const float* __restrict__ W_ih, const float* __restrict__ W_hh,
    const float* __restrict__ b_ih, const float* __restrict__ b_hh,
    const float* __restrict__ w1, const float* __restrict__ b1,
    const float* __restrict__ w2, const float* __restrict__ b2,
    const float* __restrict__ w3, const float* __restrict__ b3,
    float* __restrict__ out)
{
    const int tid = (int)threadIdx.x;
    const int t = tid >> 4;
    const int u = tid & 15;
    const bool valid = (t < NT);

    // Pre-permuted weight tables in LDS, indexed [j][u]:
    //   entry multiplies ring value x[(u-j)&15] at substep j.
    // [j][u] layout => lanes with equal u across task rows read the SAME address
    // (LDS broadcast), distinct u are 16B/8B apart (<=2-way bank aliasing, free).
    __shared__ float4 tabA[16][16];  // {whh_i, whh_f, whh_g, whh_o} permuted
    __shared__ float2 tabB[16][16];  // {w1 row u, w1 row 16+u} permuted
    __shared__ float4 tabC[16][16];  // {w2AA, w2AB, w2BA, w2BB} permuted
    __shared__ float terr[NT];

    // Build tables: 256 (j,u) pairs over 128 threads, 2 each. Straight-line,
    // no divergence; guarded loads (pad slots = 0).
#pragma unroll
    for (int p = 0; p < 2; ++p) {
        const int pair = tid + p * 128;
        const int j = pair >> 4;
        const int w = pair & 15;                  // table's "u"
        const int idx = (w - j) & 15;             // ring source index
        const bool hv = (w < HID) && (idx < HID);
        float4 wa;
        wa.x = hv ? W_hh[(0 * HID + w) * HID + idx] : 0.0f;
        wa.y = hv ? W_hh[(1 * HID + w) * HID + idx] : 0.0f;
        wa.z = hv ? W_hh[(2 * HID + w) * HID + idx] : 0.0f;
        wa.w = hv ? W_hh[(3 * HID + w) * HID + idx] : 0.0f;
        tabA[j][w] = wa;
        float2 wb;
        wb.x = (idx < HID) ? w1[w * HID + idx] : 0.0f;                       // h1[w]
        wb.y = (w < 4 && idx < HID) ? w1[(16 + w) * HID + idx] : 0.0f;       // h1[16+w]
        tabB[j][w] = wb;
        float4 wc;
        wc.x = w2[w * 2 * HID + idx];                                        // h2[w]   <- h1A ring
        wc.y = (idx < 4) ? w2[w * 2 * HID + 16 + idx] : 0.0f;                // h2[w]   <- h1B ring
        wc.z = (w < 4) ? w2[(16 + w) * 2 * HID + idx] : 0.0f;                // h2[16+w]<- h1A ring
        wc.w = (w < 4 && idx < 4) ? w2[(16 + w) * 2 * HID + 16 + idx] : 0.0f;// h2[16+w]<- h1B ring
        tabC[j][w] = wc;
    }

    // ---- per-lane scalars (small register working set; ~30 VGPRs) ----
    const unsigned m1 = decode_mask(go1);
    const unsigned m2 = decode_mask(go2);
    const float om = valid ? omega[t] : 0.0f;
    const bool is_g1 = (fabsf(om - 0.4f) < 1e-4f) || (fabsf(om - 0.8f) < 1e-4f);
    const float scale = is_g1 ? 0.2f : 0.4f;
    const unsigned msk = is_g1 ? m1 : m2;
    const float base = (om - 0.6f) / scale;

    const bool gv = valid && (u < HID);
    const float wihs0 = gv ? W_ih[(0 * HID + u) * 2 + 0] : 0.0f;
    const float wiha0 = gv ? W_ih[(0 * HID + u) * 2 + 1] : 0.0f;
    const float wihs1 = gv ? W_ih[(1 * HID + u) * 2 + 0] : 0.0f;
    const float wiha1 = gv ? W_ih[(1 * HID + u) * 2 + 1] : 0.0f;
    const float wihs2 = gv ? W_ih[(2 * HID + u) * 2 + 0] : 0.0f;
    const float wiha2 = gv ? W_ih[(2 * HID + u) * 2 + 1] : 0.0f;
    const float wihs3 = gv ? W_ih[(3 * HID + u) * 2 + 0] : 0.0f;
    const float wiha3 = gv ? W_ih[(3 * HID + u) * 2 + 1] : 0.0f;
    const float bgi = gv ? (b_ih[0 * HID + u] + b_hh[0 * HID + u]) : 0.0f;
    const float bgf = gv ? (b_ih[1 * HID + u] + b_hh[1 * HID + u]) : 0.0f;
    const float bgg = gv ? (b_ih[2 * HID + u] + b_hh[2 * HID + u]) : 0.0f;
    const float bgo = gv ? (b_ih[3 * HID + u] + b_hh[3 * HID + u]) : 0.0f;
    const float b1a = valid ? b1[u] : 0.0f;
    const float b1b = (valid && u < 4) ? b1[16 + u] : 0.0f;
    const float b2a = valid ? b2[u] : 0.0f;
    const float b2b = (valid && u < 4) ? b2[16 + u] : 0.0f;
    const float w3a = valid ? w3[u] : 0.0f;
    const float w3b = (valid && u < 4) ? w3[16 + u] : 0.0f;
    const float b3v = b3[0];

    __syncthreads();

    // ---- rollout: rolled loop (compact I-footprint), all state in registers ----
    float s = 0.0f, c = 0.0f, h = 0.0f, err = 0.0f;
    float hn0 = 0.0f, hn1 = 0.0f, hn2 = 0.0f, hn3 = 0.0f;  // sum_j whh[g][j]*h[j]
    float nz = valid ? noise[t * NS] : 0.0f;

#pragma unroll 1
    for (int st = 0; st < NS; ++st) {
        const float ahv = (((msk >> st) & 1u) ? base : 0.0f) + nz;
        const int stn = (st < NS - 1) ? st + 1 : st;       // prefetch next noise
        nz = valid ? noise[t * NS + stn] : 0.0f;

        // LSTM gates (hn* carried from previous step's h-sweep; zero at st=0)
        const float a0 = hn0 + bgi + wihs0 * s + wiha0 * ahv;
        const float a1 = hn1 + bgf + wihs1 * s + wiha1 * ahv;
        const float a2 = hn2 + bgg + wihs2 * s + wiha2 * ahv;
        const float a3 = hn3 + bgo + wihs3 * s + wiha3 * ahv;
        const float ig = sigf(a0);
        const float fg = sigf(a1);
        const float gg = tanh_fast(a2);
        const float og = sigf(a3);
        c = fmaf(fg, c, ig * gg);
        h = og * tanh_fast(c);          // lanes u>=10: weights/bias 0 -> h stays 0

        // Sweep 1: ring-rotate h; accumulate layer-1 (this step) and
        // whh·h (next step's gates) in the same pass.
        float x1a = b1a, x1b = b1b;
        hn0 = hn1 = hn2 = hn3 = 0.0f;
#define S1(J, RV) { const float r_ = (RV); \
        const float4 wa_ = tabA[J][u]; const float2 wb_ = tabB[J][u]; \
        hn0 = fmaf(wa_.x, r_, hn0); hn1 = fmaf(wa_.y, r_, hn1); \
        hn2 = fmaf(wa_.z, r_, hn2); hn3 = fmaf(wa_.w, r_, hn3); \
        x1a = fmaf(wb_.x, r_, x1a); x1b = fmaf(wb_.y, r_, x1b); }
        S1(0, h)
        S1(1,  ROTF(h, 1))  S1(2,  ROTF(h, 2))  S1(3,  ROTF(h, 3))
        S1(4,  ROTF(h, 4))  S1(5,  ROTF(h, 5))  S1(6,  ROTF(h, 6))
        S1(7,  ROTF(h, 7))  S1(8,  ROTF(h, 8))  S1(9,  ROTF(h, 9))
        S1(10, ROTF(h, 10)) S1(11, ROTF(h, 11)) S1(12, ROTF(h, 12))
        S1(13, ROTF(h, 13)) S1(14, ROTF(h, 14)) S1(15, ROTF(h, 15))

        const float h1a = fmaxf(x1a, 0.0f);     // h1[u]
        const float h1b = fmaxf(x1b, 0.0f);     // h1[16+u] (u<4; else exactly 0)

        // Sweep 2: rotate both h1 planes; layer-2.
        float x2a = b2a, x2b = b2b;
#define S2(J, RA, RB) { const float ra_ = (RA), rb_ = (RB); \
        const float4 wc_ = tabC[J][u]; \
        x2a = fmaf(wc_.x, ra_, x2a); x2a = fmaf(wc_.y, rb_, x2a); \
        x2b = fmaf(wc_.z, ra_, x2b); x2b = fmaf(wc_.w, rb_, x2b); }
        S2(0, h1a, h1b)
        S2(1,  ROTF(h1a, 1),  ROTF(h1b, 1))  S2(2,  ROTF(h1a, 2),  ROTF(h1b, 2))
        S2(3,  ROTF(h1a, 3),  ROTF(h1b, 3))  S2(4,  ROTF(h1a, 4),  ROTF(h1b, 4))
        S2(5,  ROTF(h1a, 5),  ROTF(h1b, 5))  S2(6,  ROTF(h1a, 6),  ROTF(h1b, 6))
        S2(7,  ROTF(h1a, 7),  ROTF(h1b, 7))  S2(8,  ROTF(h1a, 8),  ROTF(h1b, 8))
        S2(9,  ROTF(h1a, 9),  ROTF(h1b, 9))  S2(10, ROTF(h1a, 10), ROTF(h1b, 10))
        S2(11, ROTF(h1a, 11), ROTF(h1b, 11)) S2(12, ROTF(h1a, 12), ROTF(h1b, 12))
        S2(13, ROTF(h1a, 13), ROTF(h1b, 13)) S2(14, ROTF(h1a, 14), ROTF(h1b, 14))
        S2(15, ROTF(h1a, 15), ROTF(h1b, 15))

        const float h2a = fmaxf(x2a, 0.0f);     // h2[u]
        const float h2b = fmaxf(x2b, 0.0f);     // h2[16+u] (u<4; else 0)

        // ar = w3·h2 + b3: per-lane partial, then 4-level DPP butterfly
        // (xor1, xor2, xor7=half_mirror, xor15=mirror spans all 16 lanes;
        //  commutative adds -> bit-identical total in every lane of the row).
        float red = fmaf(w3a, h2a, w3b * h2b);
        red += BFLY(red, 0xB1);   // quad_perm [1,0,3,2]  : lane ^ 1
        red += BFLY(red, 0x4E);   // quad_perm [2,3,0,1]  : lane ^ 2
        red += BFLY(red, 0x141);  // row_half_mirror      : lane ^ 7
        red += BFLY(red, 0x140);  // row_mirror           : lane ^ 15

        s += red + b3v;
        const float d = s - om;
        err = fmaf(d, d, err);
    }

    if (valid && u == 0) terr[t] = err;
    __syncthreads();
    if (tid == 0)
        out[0] = terr[0] + terr[1] + terr[2] + terr[3] + terr[4];
}

extern "C" void kernel_launch(void* const* d_in, const int* in_sizes, int n_in,
                              void* d_out, int out_size, void* d_ws, size_t ws_size,
                              hipStream_t stream) {
    rnnae_kernel<<<1, 128, 0, stream>>>(
        (const float*)d_in[0],   // omega [5]
        (const float*)d_in[1],   // noise [5,10]
        d_in[2],                 // go1_mask [10] (bool, decoded in-kernel)
        d_in[3],                 // go2_mask [10]
        (const float*)d_in[4],   // W_ih [40,2]
        (const float*)d_in[5],   // W_hh [40,10]
        (const float*)d_in[6],   // b_ih [40]
        (const float*)d_in[7],   // b_hh [40]
        (const float*)d_in[8],   // w1 [20,10]
        (const float*)d_in[9],   // b1 [20]
        (const float*)d_in[10],  // w2 [20,20]
        (const float*)d_in[11],  // b2 [20]
        (const float*)d_in[12],  // w3 [1,20]
        (const float*)d_in[13],  // b3 [1]
        (float*)d_out);
}